// Round 5
// baseline (309.927 us; speedup 1.0000x reference)
//
#include <hip/hip_runtime.h>

// Reference numpy/jnp math is UNFUSED IEEE f32 — disable FMA contraction so
// the catastrophically-cancelled det (compared against EPS=1e-7) and the
// 1/det-scaled shifts are bit-identical to the reference.
#pragma clang fp contract(off)

// Problem constants (from setup_inputs): B=2, C=4, D=6, H=512, W=512, f32.
constexpr int B_ = 2, C_ = 4, D_ = 6, H_ = 512, W_ = 512;
constexpr int HW_  = H_ * W_;        // 262144
constexpr int DHW_ = D_ * HW_;       // 1572864
constexpr int BC_  = B_ * C_;        // 8
constexpr int TOT_ = BC_ * DHW_;     // 12582912

#define EPS_ 1e-7f
#define MAX_SHIFT_ 0.6f
#define BONUS_ 10.0f
#define N_ITERS_ 5

// DIAGNOSTIC PROBE ROUND: run the full per-voxel body TWICE (identical work,
// identical stores → bit-exact). Doubles kernel duration past the ~120us
// profiler top-5 cutoff so we finally see OUR dispatch's counters
// (VALUBusy / Occupancy / WRITE_SIZE). Pass 2 re-does everything thanks to
// the asm memory clobber (defeats load hoisting / store CSE).
#define REPS_ 2

// ---------------------------------------------------------------------------
// 3x3x3 quadratic-fit Cramer solve; p points at the (interior) center voxel.
// Op ordering mirrors the reference exactly (f32, no contraction).
__device__ __forceinline__ void solve3(const float* __restrict__ p,
                                       float& sx, float& sy, float& ss,
                                       float& gds, bool& sol)
{
    #pragma clang fp contract(off)
    float c    = p[0];
    float xp   = p[1],          xm   = p[-1];
    float yp   = p[W_],         ym   = p[-W_];
    float spv  = p[HW_],        smv  = p[-HW_];
    float xpyp = p[W_ + 1],     xmyp = p[W_ - 1];
    float xpym = p[-W_ + 1],    xmym = p[-W_ - 1];
    float xpsp = p[HW_ + 1],    xmsp = p[HW_ - 1];
    float xpsm = p[-HW_ + 1],   xmsm = p[-HW_ - 1];
    float ypsp = p[HW_ + W_],   ymsp = p[HW_ - W_];
    float ypsm = p[-HW_ + W_],  ymsm = p[-HW_ - W_];

    float gx = 0.5f * (xp - xm);
    float gy = 0.5f * (yp - ym);
    float gs = 0.5f * (spv - smv);
    float dxx = xp - 2.0f * c + xm;
    float dyy = yp - 2.0f * c + ym;
    float dss = spv - 2.0f * c + smv;
    float dxy = 0.25f * (xpyp - xmyp - xpym + xmym);
    float dxs = 0.25f * (xpsp - xmsp - xpsm + xmsm);
    float dys = 0.25f * (ypsp - ymsp - ypsm + ymsm);

    float cf00 = dyy * dss - dys * dys;
    float cf01 = dxy * dss - dys * dxs;
    float cf02 = dxy * dys - dyy * dxs;
    float det  = dxx * cf00 - dxy * cf01 + dxs * cf02;
    sol = fabsf(det) > EPS_;
    float sd = sol ? det : 1.0f;
    float r0 = -gx, r1 = -gy, r2 = -gs;
    sx = (r0 * cf00 - dxy * (r1 * dss - dys * r2) + dxs * (r1 * dys - dyy * r2)) / sd;
    sy = (dxx * (r1 * dss - dys * r2) - r0 * cf01 + dxs * (dxy * r2 - r1 * dxs)) / sd;
    ss = (dxx * (dyy * r2 - r1 * dys) - dxy * (dxy * r2 - r1 * dxs) + r0 * cf02) / sd;
    gds = gx * sx + gy * sy + gs * ss;
}

// ---------------------------------------------------------------------------
// Round-0 structure (best measured: one thread per voxel), wrapped in a
// REPS_ loop for profiling visibility. Each pass is bit-identical.
__global__ __launch_bounds__(256)
void AdaptiveQuadInterp3d_kernel(const float* __restrict__ x,
                                 const int* __restrict__ mask,
                                 float* __restrict__ out)
{
    int idx = blockIdx.x * 256 + threadIdx.x;

    int w  = idx & (W_ - 1);
    int h  = (idx >> 9) & (H_ - 1);
    int t  = idx >> 18;          // bc*D + d   (HW = 2^18)
    int d  = t % D_;
    int bc = t / D_;
    int sp = idx - bc * DHW_;

    #pragma unroll 1
    for (int rep = 0; rep < REPS_; ++rep) {
        asm volatile("" ::: "memory");   // force full re-execution per pass

        float xc = x[idx];
        int   m  = mask[idx];            // bool input materialized as int32

        // Default coords: cs=d, cx=w, cy=h. Streamed nontemporally; seed
        // lanes overwrite below (same thread, same address → program-order
        // safe).
        float* cb = out + (bc * 3) * DHW_ + sp;
        __builtin_nontemporal_store((float)d, cb);
        __builtin_nontemporal_store((float)w, cb + DHW_);
        __builtin_nontemporal_store((float)h, cb + 2 * DHW_);

        float yv = xc;               // y_max default = x

        // Wave-uniform skip: 0.999^64 ≈ 94% of waves have no seeds.
        if (__ballot(m != 0) != 0ULL) {
            if (m != 0) {
                const float* xb = x + bc * DHW_;
                int dsd = 0, dsh = 0, dsw = 0;
                bool valid = true;
                float shx = 0.0f, shy = 0.0f, shs = 0.0f, gk = 0.0f;

                // Exact early termination (bit-exact vs reference):
                //  - !sol → valid false forever, outputs become defaults.
                //  - all-zero steps = fixed point: later iters identical.
                #pragma unroll 1
                for (int it = 0; it < N_ITERS_; ++it) {
                    int di = min(max(d + dsd, 1), D_ - 2);
                    int hi = min(max(h + dsh, 1), H_ - 2);
                    int wi = min(max(w + dsw, 1), W_ - 2);
                    const float* p = xb + di * HW_ + hi * W_ + wi;

                    float sx, sy, ssv, gds; bool sol;
                    solve3(p, sx, sy, ssv, gds, sol);

                    if (!sol) { valid = false; break; }

                    shx = sx; shy = sy; shs = ssv; gk = gds;

                    int stx = (shx > MAX_SHIFT_) ? 1 : ((shx < -MAX_SHIFT_) ? -1 : 0);
                    int sty = (shy > MAX_SHIFT_) ? 1 : ((shy < -MAX_SHIFT_) ? -1 : 0);
                    int sts = (shs > MAX_SHIFT_) ? 1 : ((shs < -MAX_SHIFT_) ? -1 : 0);
                    dsw += stx;
                    dsh += sty;
                    dsd += sts;
                    valid = (abs(dsd) <= 1) && (abs(dsh) <= 1) && (abs(dsw) <= 1);
                    if (!valid) break;                  // radius breach — exact
                    if ((stx | sty | sts) == 0) break;  // fixed point — exact
                }

                if (valid) {
                    int di = min(max(d + dsd, 1), D_ - 2);
                    int hi = min(max(h + dsh, 1), H_ - 2);
                    int wi = min(max(w + dsw, 1), W_ - 2);
                    float cur = xb[di * HW_ + hi * W_ + wi];
                    __builtin_nontemporal_store((float)(d + dsd) + shs, cb);
                    __builtin_nontemporal_store((float)(w + dsw) + shx, cb + DHW_);
                    __builtin_nontemporal_store((float)(h + dsh) + shy, cb + 2 * DHW_);
                    yv = (cur + 0.5f * gk) + BONUS_;
                } else {
                    yv = xc + BONUS_;   // coord defaults already stored
                }
            }
        }

        __builtin_nontemporal_store(yv, out + BC_ * 3 * DHW_ + idx);
    }
}

extern "C" void kernel_launch(void* const* d_in, const int* in_sizes, int n_in,
                              void* d_out, int out_size, void* d_ws, size_t ws_size,
                              hipStream_t stream) {
    const float* x    = (const float*)d_in[0];
    const int*   mask = (const int*)d_in[1];
    float*       out  = (float*)d_out;

    int blocks = TOT_ / 256;     // 49152
    AdaptiveQuadInterp3d_kernel<<<blocks, 256, 0, stream>>>(x, mask, out);
}

// Round 6
// 265.511 us; speedup vs baseline: 1.1673x; 1.1673x over previous
//
#include <hip/hip_runtime.h>

// Reference numpy/jnp math is UNFUSED IEEE f32 — disable FMA contraction so
// the catastrophically-cancelled det (compared against EPS=1e-7) and the
// 1/det-scaled shifts are bit-identical to the reference.
#pragma clang fp contract(off)

// Problem constants (from setup_inputs): B=2, C=4, D=6, H=512, W=512, f32.
constexpr int B_ = 2, C_ = 4, D_ = 6, H_ = 512, W_ = 512;
constexpr int HW_  = H_ * W_;        // 262144
constexpr int DHW_ = D_ * HW_;       // 1572864
constexpr int BC_  = B_ * C_;        // 8
constexpr int TOT_ = BC_ * DHW_;     // 12582912

#define EPS_ 1e-7f
#define MAX_SHIFT_ 0.6f
#define BONUS_ 10.0f
#define N_ITERS_ 5

// ---------------------------------------------------------------------------
// 3x3x3 quadratic-fit Cramer solve; p points at the (interior) center voxel.
// Op ordering mirrors the reference exactly (f32, no contraction).
__device__ __forceinline__ void solve3(const float* __restrict__ p,
                                       float& sx, float& sy, float& ss,
                                       float& gds, bool& sol)
{
    #pragma clang fp contract(off)
    float c    = p[0];
    float xp   = p[1],          xm   = p[-1];
    float yp   = p[W_],         ym   = p[-W_];
    float spv  = p[HW_],        smv  = p[-HW_];
    float xpyp = p[W_ + 1],     xmyp = p[W_ - 1];
    float xpym = p[-W_ + 1],    xmym = p[-W_ - 1];
    float xpsp = p[HW_ + 1],    xmsp = p[HW_ - 1];
    float xpsm = p[-HW_ + 1],   xmsm = p[-HW_ - 1];
    float ypsp = p[HW_ + W_],   ymsp = p[HW_ - W_];
    float ypsm = p[-HW_ + W_],  ymsm = p[-HW_ - W_];

    float gx = 0.5f * (xp - xm);
    float gy = 0.5f * (yp - ym);
    float gs = 0.5f * (spv - smv);
    float dxx = xp - 2.0f * c + xm;
    float dyy = yp - 2.0f * c + ym;
    float dss = spv - 2.0f * c + smv;
    float dxy = 0.25f * (xpyp - xmyp - xpym + xmym);
    float dxs = 0.25f * (xpsp - xmsp - xpsm + xmsm);
    float dys = 0.25f * (ypsp - ymsp - ypsm + ymsm);

    float cf00 = dyy * dss - dys * dys;
    float cf01 = dxy * dss - dys * dxs;
    float cf02 = dxy * dys - dyy * dxs;
    float det  = dxx * cf00 - dxy * cf01 + dxs * cf02;
    sol = fabsf(det) > EPS_;
    float sd = sol ? det : 1.0f;
    float r0 = -gx, r1 = -gy, r2 = -gs;
    sx = (r0 * cf00 - dxy * (r1 * dss - dys * r2) + dxs * (r1 * dys - dyy * r2)) / sd;
    sy = (dxx * (r1 * dss - dys * r2) - r0 * cf01 + dxs * (dxy * r2 - r1 * dxs)) / sd;
    ss = (dxx * (dyy * r2 - r1 * dys) - dxy * (dxy * r2 - r1 * dxs) + r0 * cf02) / sd;
    gds = gx * sx + gy * sy + gs * ss;
}

// ---------------------------------------------------------------------------
// One fused pass, one thread per voxel — the empirically fastest structure:
// REPS=2 probe (round 5) showed the marginal full pass costs ~43 µs ≈ pure
// traffic at the fill-demonstrated 6.6 TB/s, i.e. this kernel runs at ~92%
// of the achievable memory roofline (302 MB mandatory traffic / ~46 µs floor,
// ~50 µs actual). Vectorized variants (x4, x8 voxels/thread) regressed by
// diluting the wave-uniform seed skip (94% → 77% → 60% of waves skipping).
__global__ __launch_bounds__(256)
void AdaptiveQuadInterp3d_kernel(const float* __restrict__ x,
                                 const int* __restrict__ mask,
                                 float* __restrict__ out)
{
    int idx = blockIdx.x * 256 + threadIdx.x;

    int w  = idx & (W_ - 1);
    int h  = (idx >> 9) & (H_ - 1);
    int t  = idx >> 18;          // bc*D + d   (HW = 2^18)
    int d  = t % D_;
    int bc = t / D_;
    int sp = idx - bc * DHW_;

    float xc = x[idx];
    int   m  = mask[idx];        // bool input materialized as int32

    // Default coords: cs=d, cx=w, cy=h. Streamed nontemporally; seed lanes
    // overwrite below (same thread, same address → program-order safe).
    float* cb = out + (bc * 3) * DHW_ + sp;
    __builtin_nontemporal_store((float)d, cb);
    __builtin_nontemporal_store((float)w, cb + DHW_);
    __builtin_nontemporal_store((float)h, cb + 2 * DHW_);

    float yv = xc;               // y_max default = x

    // Wave-uniform skip: 0.999^64 ≈ 94% of waves have no seeds.
    if (__ballot(m != 0) != 0ULL) {
        if (m != 0) {
            const float* xb = x + bc * DHW_;
            int dsd = 0, dsh = 0, dsw = 0;
            bool valid = true;
            float shx = 0.0f, shy = 0.0f, shs = 0.0f, gk = 0.0f;

            // Exact early termination:
            //  - `valid` is monotone: once false, shifts mask to 0 forever and
            //    outputs are the defaults (+BONUS on y). Break.
            //  - valid with all-zero steps = fixed point: later iterations
            //    recompute identical values. Break. Bit-exact vs reference.
            #pragma unroll 1
            for (int it = 0; it < N_ITERS_; ++it) {
                int di = min(max(d + dsd, 1), D_ - 2);
                int hi = min(max(h + dsh, 1), H_ - 2);
                int wi = min(max(w + dsw, 1), W_ - 2);
                const float* p = xb + di * HW_ + hi * W_ + wi;

                float sx, sy, ssv, gds; bool sol;
                solve3(p, sx, sy, ssv, gds, sol);

                if (!sol) { valid = false; break; }   // defaults — exact

                shx = sx; shy = sy; shs = ssv; gk = gds;

                int stx = (shx > MAX_SHIFT_) ? 1 : ((shx < -MAX_SHIFT_) ? -1 : 0);
                int sty = (shy > MAX_SHIFT_) ? 1 : ((shy < -MAX_SHIFT_) ? -1 : 0);
                int sts = (shs > MAX_SHIFT_) ? 1 : ((shs < -MAX_SHIFT_) ? -1 : 0);
                dsw += stx;
                dsh += sty;
                dsd += sts;
                valid = (abs(dsd) <= 1) && (abs(dsh) <= 1) && (abs(dsw) <= 1);
                if (!valid) break;                    // radius breach — exact
                if ((stx | sty | sts) == 0) break;    // fixed point — exact
            }

            if (valid) {
                int di = min(max(d + dsd, 1), D_ - 2);
                int hi = min(max(h + dsh, 1), H_ - 2);
                int wi = min(max(w + dsw, 1), W_ - 2);
                float cur = xb[di * HW_ + hi * W_ + wi];
                __builtin_nontemporal_store((float)(d + dsd) + shs, cb);
                __builtin_nontemporal_store((float)(w + dsw) + shx, cb + DHW_);
                __builtin_nontemporal_store((float)(h + dsh) + shy, cb + 2 * DHW_);
                yv = (cur + 0.5f * gk) + BONUS_;
            } else {
                yv = xc + BONUS_;   // coord defaults already stored
            }
        }
    }

    __builtin_nontemporal_store(yv, out + BC_ * 3 * DHW_ + idx);
}

extern "C" void kernel_launch(void* const* d_in, const int* in_sizes, int n_in,
                              void* d_out, int out_size, void* d_ws, size_t ws_size,
                              hipStream_t stream) {
    const float* x    = (const float*)d_in[0];
    const int*   mask = (const int*)d_in[1];
    float*       out  = (float*)d_out;

    int blocks = TOT_ / 256;     // 49152
    AdaptiveQuadInterp3d_kernel<<<blocks, 256, 0, stream>>>(x, mask, out);
}